// Round 6
// baseline (79.766 us; speedup 1.0000x reference)
//
#include <hip/hip_runtime.h>
#include <math.h>

// Problem constants (setup_inputs is fixed: P=4, A=4096)
#define A_ATOMS 4096
#define P_POSES 4
#define N_TOT   (A_ATOMS * P_POSES)
#define TILE    128
#define NTILES  (A_ATOMS / TILE)             // 32
#define JG      8                            // j-tiles per block (128x1024 strip)
#define NJG     (NTILES / JG)                // 4 aligned j-groups
// groups per row bi: NJG - bi/JG; total per pose = 8*4 + 8*3 + 8*2 + 8*1 = 80
#define NSTRIPS 80
#define LJ_T    512                          // 8 waves per block

// forward-kinematics segmented scan geometry (verified R3 structure)
#define SEG     64                            // atoms per segment = 1 wave
#define NSEG    (A_ATOMS / SEG)               // 64 segments per pose
#define APPLY_T 256                           // fk_apply threads (1 atom/thread)
#define APPLY_B (A_ATOMS / APPLY_T)           // 16 blocks per pose

typedef float v2f __attribute__((ext_vector_type(2)));

__device__ __constant__ float c_SIGMA2  = 1.9f * 1.9f;
__device__ __constant__ float c_4EPS    = 0.8f;   // 4 * 0.2
__device__ __constant__ float c_R2SOFT  = 0.25f;

// ---------------- rigid transform (3x4 row-major: r|t) ----------------
struct RT { float m[12]; };

__device__ inline RT rt_identity() {
    RT v;
    v.m[0]=1.f; v.m[1]=0.f; v.m[2]=0.f;  v.m[3]=0.f;
    v.m[4]=0.f; v.m[5]=1.f; v.m[6]=0.f;  v.m[7]=0.f;
    v.m[8]=0.f; v.m[9]=0.f; v.m[10]=1.f; v.m[11]=0.f;
    return v;
}

// C = A o B  (left-to-right chain product: cum = cum @ ht)
__device__ inline RT rt_compose(const RT& a, const RT& b) {
    RT c;
#pragma unroll
    for (int i = 0; i < 3; ++i) {
        float a0 = a.m[i*4+0], a1 = a.m[i*4+1], a2 = a.m[i*4+2];
        c.m[i*4+0] = fmaf(a0, b.m[0], fmaf(a1, b.m[4],  a2*b.m[8]));
        c.m[i*4+1] = fmaf(a0, b.m[1], fmaf(a1, b.m[5],  a2*b.m[9]));
        c.m[i*4+2] = fmaf(a0, b.m[2], fmaf(a1, b.m[6],  a2*b.m[10]));
        c.m[i*4+3] = fmaf(a0, b.m[3], fmaf(a1, b.m[7],  fmaf(a2, b.m[11], a.m[i*4+3])));
    }
    return c;
}

// lane-wise pull of an RT from (lane - off) within the wave
__device__ inline RT rt_shfl_up(const RT& a, int off) {
    RT r;
#pragma unroll
    for (int i = 0; i < 12; ++i) r.m[i] = __shfl_up(a.m[i], off, 64);
    return r;
}

// Accurate trig kept on purpose: the 4096-long compose chain amplifies per-HT
// error; absmax margin vs threshold is only ~2.2x.
__device__ inline RT local_ht(const float* __restrict__ dof) {
    float phi = dof[0], th = dof[1];
    float d = fmaf(0.25f, tanhf(dof[2]), 1.5f);
    float sp, cp, st, ct;
    sincosf(phi, &sp, &cp);
    sincosf(th,  &st, &ct);
    RT h;
    h.m[0] = cp*ct; h.m[1] = -sp; h.m[2]  = cp*st; h.m[3]  = d*cp*ct;
    h.m[4] = sp*ct; h.m[5] =  cp; h.m[6]  = sp*st; h.m[7]  = d*sp*ct;
    h.m[8] = -st;   h.m[9] = 0.f; h.m[10] = ct;    h.m[11] = -d*st;
    return h;
}

// ---------------- kernel 1a: per-segment inclusive scan (R3-verified) ----------
__global__ __launch_bounds__(SEG) void fk_scan(const float* __restrict__ dofs,
                                               float* __restrict__ Tx,
                                               float* __restrict__ Ty,
                                               float* __restrict__ Tz,
                                               float4* __restrict__ S0,
                                               float4* __restrict__ S1,
                                               float4* __restrict__ S2) {
    const int pose = blockIdx.x >> 6;        // NSEG = 64
    const int seg  = blockIdx.x & (NSEG - 1);
    const int lane = threadIdx.x;
    const int g    = pose * A_ATOMS + seg * SEG + lane;

    RT v = local_ht(dofs + (size_t)g * 9);

    // inclusive wave scan, earlier lane on the LEFT
#pragma unroll
    for (int off = 1; off < 64; off <<= 1) {
        RT l = rt_shfl_up(v, off);
        if (lane >= off) v = rt_compose(l, v);
    }

    // segment-relative translation for this atom (all that apply needs)
    Tx[g] = v.m[3]; Ty[g] = v.m[7]; Tz[g] = v.m[11];

    // segment total (full RT)
    if (lane == 63) {
        int s = pose * NSEG + seg;
        S0[s] = make_float4(v.m[0], v.m[1], v.m[2],  v.m[3]);
        S1[s] = make_float4(v.m[4], v.m[5], v.m[6],  v.m[7]);
        S2[s] = make_float4(v.m[8], v.m[9], v.m[10], v.m[11]);
    }
}

// ---------------- kernel 1b: totals scan + apply + scatter (R3-verified) --------
// Output is now PACKED float4 (x,y,z,0): one 16B store here, and lj stages each
// atom with a single global_load_dwordx4 instead of three scalar dwords (G13).
__global__ __launch_bounds__(APPLY_T) void fk_apply(const int* __restrict__ kid,
                                                    const float* __restrict__ Tx,
                                                    const float* __restrict__ Ty,
                                                    const float* __restrict__ Tz,
                                                    const float4* __restrict__ S0,
                                                    const float4* __restrict__ S1,
                                                    const float4* __restrict__ S2,
                                                    float4* __restrict__ C4,
                                                    float* __restrict__ out) {
    __shared__ float4 e0[NSEG], e1[NSEG], e2[NSEG];

    const int pose = blockIdx.y;
    const int blk  = blockIdx.x;
    const int tid  = threadIdx.x;
    if (blk == 0 && tid == 0) out[pose] = 0.f;

    if (tid < 64) {      // exactly wave 0: all 64 lanes active for shuffles
        int s = pose * NSEG + tid;
        float4 a0 = S0[s], a1 = S1[s], a2 = S2[s];
        RT v;
        v.m[0]=a0.x; v.m[1]=a0.y; v.m[2]=a0.z;  v.m[3]=a0.w;
        v.m[4]=a1.x; v.m[5]=a1.y; v.m[6]=a1.z;  v.m[7]=a1.w;
        v.m[8]=a2.x; v.m[9]=a2.y; v.m[10]=a2.z; v.m[11]=a2.w;
#pragma unroll
        for (int off = 1; off < 64; off <<= 1) {
            RT l = rt_shfl_up(v, off);
            if (tid >= off) v = rt_compose(l, v);
        }
        // exclusive prefix: shift right by one, identity at segment 0
        RT ex = rt_shfl_up(v, 1);
        if (tid == 0) ex = rt_identity();
        e0[tid] = make_float4(ex.m[0], ex.m[1], ex.m[2],  ex.m[3]);
        e1[tid] = make_float4(ex.m[4], ex.m[5], ex.m[6],  ex.m[7]);
        e2[tid] = make_float4(ex.m[8], ex.m[9], ex.m[10], ex.m[11]);
    }
    __syncthreads();

    const int a = blk * APPLY_T + tid;         // coalesced; a>>6 wave-uniform -> LDS broadcast
    const int g = pose * A_ATOMS + a;
    float rx = Tx[g], ry = Ty[g], rz = Tz[g];
    float4 x0 = e0[a >> 6], x1 = e1[a >> 6], x2 = e2[a >> 6];
    float tx = fmaf(x0.x, rx, fmaf(x0.y, ry, fmaf(x0.z, rz, x0.w)));
    float ty = fmaf(x1.x, rx, fmaf(x1.y, ry, fmaf(x1.z, rz, x1.w)));
    float tz = fmaf(x2.x, rx, fmaf(x2.y, ry, fmaf(x2.z, rz, x2.w)));
    C4[kid[g]] = make_float4(tx, ty, tz, 0.f);
}

// ---------------- kernel 2: LJ, 8 j-tiles per 512-thread block -------------------
// R5 post-mortem: amortization is the lever (41.5 -> ~27 us), but waves/SIMD was
// only 2.25. This version: 320 blocks x 8 waves = 2560 waves (2.5/SIMD, TLP up),
// per-block tiles 4 -> up to 8 (fixed cost halved), float4 staging (1 dwordx4 vs
// 3 dwords), and single-barrier double-buffered j-tiles (prefetch lands in
// buf[1-cur]; that buffer was last read before the PREVIOUS barrier -> safe).
// Per-thread mapping: 4 i-rows x 8 j-cols. Inner pair math unchanged.
__global__ __launch_bounds__(LJ_T) void lj_kernel(const float4* __restrict__ C4,
                                                  float* __restrict__ out) {
    const int pose = blockIdx.y;
    // map blockIdx.x -> (bi, jg): row bi has NJG - bi/JG aligned j-groups
    int rr = blockIdx.x, bi = 0;
    while (rr >= NJG - (bi >> 3)) { rr -= NJG - (bi >> 3); ++bi; }
    const int jg = (bi >> 3) + rr;           // absolute j-group (j-tiles jg*8 .. jg*8+7)
    const int t0 = (jg == (bi >> 3)) ? (bi & 7) : 0;   // skip tiles left of diagonal

    __shared__ float sxi[TILE], syi[TILE], szi[TILE];
    __shared__ float sxj[2][TILE], syj[2][TILE], szj[2][TILE];

    const int tid = threadIdx.x;
    const float4* Cp = C4 + pose * A_ATOMS;

    if (tid < TILE) {
        float4 c = Cp[bi * TILE + tid];
        sxi[tid] = c.x; syi[tid] = c.y; szi[tid] = c.z;
    } else if (tid < 2 * TILE) {
        int t = tid - TILE;
        float4 c = Cp[(jg * JG + t0) * TILE + t];
        sxj[0][t] = c.x; syj[0][t] = c.y; szj[0][t] = c.z;
    }
    __syncthreads();

    // 32 i-groups x 16 j-groups; each thread: 4 i-rows x 8 j-cols in registers
    const int i0 = (tid & 31) * 4;
    const int j0 = (tid >> 5) * 8;

    const float SIG2 = c_SIGMA2, SOFT = c_R2SOFT;

    // i-registers: loaded ONCE for the whole 128x1024 strip
    float xi[4], yi[4], zi[4];
#pragma unroll
    for (int k = 0; k < 4; ++k) {
        xi[k] = sxi[i0 + k]; yi[k] = syi[i0 + k]; zi[k] = szi[i0 + k];
    }

    float acc = 0.f;
    int cur = 0;

    for (int t = t0; t < JG; ++t) {
        const int bj = jg * JG + t;

        // issue next j-tile's load now; LDS write deferred to after this tile's compute
        float4 p4;
        const bool pf = (t < JG - 1) && (tid >= 3 * TILE);
        if (pf) p4 = Cp[(bj + 1) * TILE + (tid - 3 * TILE)];

        if (bi != bj) {
            // off-diagonal tile: packed fp32 pairs -> v_pk_fma_f32 candidates
            v2f xj2[4], yj2[4], zj2[4];
#pragma unroll
            for (int p = 0; p < 4; ++p) {
                xj2[p] = (v2f){sxj[cur][j0 + 2*p], sxj[cur][j0 + 2*p + 1]};
                yj2[p] = (v2f){syj[cur][j0 + 2*p], syj[cur][j0 + 2*p + 1]};
                zj2[p] = (v2f){szj[cur][j0 + 2*p], szj[cur][j0 + 2*p + 1]};
            }
            const v2f soft2 = (v2f){SOFT, SOFT};
            v2f acc2 = (v2f){0.f, 0.f};
#pragma unroll
            for (int p = 0; p < 4; ++p) {
#pragma unroll
                for (int k = 0; k < 4; ++k) {
                    v2f dx = xi[k] - xj2[p];
                    v2f dy = yi[k] - yj2[p];
                    v2f dz = zi[k] - zj2[p];
                    v2f r2 = __builtin_elementwise_fma(dx, dx,
                             __builtin_elementwise_fma(dy, dy,
                             __builtin_elementwise_fma(dz, dz, soft2)));
                    v2f rc = (v2f){__builtin_amdgcn_rcpf(r2.x), __builtin_amdgcn_rcpf(r2.y)};
                    v2f tt = SIG2 * rc;
                    v2f i6 = tt * tt * tt;
                    acc2 += __builtin_elementwise_fma(i6, i6, -i6);   // inv12 - inv6
                }
            }
            acc += acc2.x + acc2.y;
        } else {
            // diagonal tile: keep only i < j (scalar masked path)
            float xj[8], yj[8], zj[8];
#pragma unroll
            for (int k = 0; k < 8; ++k) {
                xj[k] = sxj[cur][j0 + k]; yj[k] = syj[cur][j0 + k]; zj[k] = szj[cur][j0 + k];
            }
#pragma unroll
            for (int jj = 0; jj < 8; ++jj) {
                int j = j0 + jj;
#pragma unroll
                for (int k = 0; k < 4; ++k) {
                    float dx = xi[k] - xj[jj], dy = yi[k] - yj[jj], dz = zi[k] - zj[jj];
                    float r2 = fmaf(dx, dx, fmaf(dy, dy, fmaf(dz, dz, SOFT)));
                    float tt = SIG2 * __builtin_amdgcn_rcpf(r2);
                    float i6 = tt * tt * tt;
                    float hh = fmaf(i6, i6, -i6);
                    acc += ((i0 + k) < j) ? hh : 0.f;
                }
            }
        }

        if (t < JG - 1) {
            if (pf) {
                int tl = tid - 3 * TILE;
                sxj[1 - cur][tl] = p4.x; syj[1 - cur][tl] = p4.y; szj[1 - cur][tl] = p4.z;
            }
            __syncthreads();                 // single barrier per tile (dbuf)
            cur ^= 1;
        }
    }
    acc *= c_4EPS;

    // wave64 reduce then cross-wave via LDS
#pragma unroll
    for (int off = 32; off > 0; off >>= 1) acc += __shfl_down(acc, off, 64);

    __shared__ float wsum[LJ_T / 64];
    int lane = tid & 63, wid = tid >> 6;
    if (lane == 0) wsum[wid] = acc;
    __syncthreads();
    if (tid == 0) {
        float s = 0.f;
#pragma unroll
        for (int w = 0; w < LJ_T / 64; ++w) s += wsum[w];
        atomicAdd(out + pose, s);
    }
}

// ---------------- launch ----------------
extern "C" void kernel_launch(void* const* d_in, const int* in_sizes, int n_in,
                              void* d_out, int out_size, void* d_ws, size_t ws_size,
                              hipStream_t stream) {
    (void)in_sizes; (void)n_in; (void)out_size; (void)ws_size;
    const float* dofs = (const float*)d_in[0];
    const int*   kid  = (const int*)d_in[2];
    float*       out  = (float*)d_out;

    // workspace layout (16B-aligned):
    //   C4:          N_TOT float4 (packed coords, kid-scattered)  256 KB
    //   Tx,Ty,Tz:    3 * N_TOT floats (segment-relative transl.)  192 KB
    //   S0,S1,S2:    3 * P*NSEG float4 (segment totals)            12 KB
    float4* C4 = (float4*)d_ws;
    float*  Tx = (float*)(C4 + N_TOT);
    float*  Ty = Tx + N_TOT;
    float*  Tz = Ty + N_TOT;
    float4* S0 = (float4*)(Tz + N_TOT);
    float4* S1 = S0 + P_POSES * NSEG;
    float4* S2 = S1 + P_POSES * NSEG;

    fk_scan<<<P_POSES * NSEG, SEG, 0, stream>>>(dofs, Tx, Ty, Tz, S0, S1, S2);
    dim3 agrid(APPLY_B, P_POSES);
    fk_apply<<<agrid, APPLY_T, 0, stream>>>(kid, Tx, Ty, Tz, S0, S1, S2, C4, out);
    dim3 grid(NSTRIPS, P_POSES);
    lj_kernel<<<grid, LJ_T, 0, stream>>>(C4, out);
}

// Round 7
// 79.602 us; speedup vs baseline: 1.0021x; 1.0021x over previous
//
#include <hip/hip_runtime.h>
#include <math.h>

// Problem constants (setup_inputs is fixed: P=4, A=4096)
#define A_ATOMS 4096
#define P_POSES 4
#define N_TOT   (A_ATOMS * P_POSES)

// forward-kinematics segmented scan geometry (R3-verified structure)
#define SEG     64                            // atoms per segment = 1 wave
#define NSEG    (A_ATOMS / SEG)               // 64 segments per pose
#define APPLY_T 256                           // fk_apply threads (1 atom/thread)
#define APPLY_B (A_ATOMS / APPLY_T)           // 16 blocks per pose

// LJ wave-independent geometry: one wave per 64x64 segment-pair
#define SEGP_PER_POSE (NSEG * (NSEG + 1) / 2) // 2080 upper-tri seg-pairs per pose
#define SEGP_TOT      (SEGP_PER_POSE * P_POSES) // 8320
#define LJW_T   512                           // 8 waves per block
#define WPB     (LJW_T / 64)                  // 8 seg-pairs per block
#define LJ_BLOCKS (SEGP_TOT / WPB)            // 1040 (2080%8==0 -> pose uniform per block)

typedef float v2f __attribute__((ext_vector_type(2)));

__device__ __constant__ float c_SIGMA2  = 1.9f * 1.9f;
__device__ __constant__ float c_4EPS    = 0.8f;   // 4 * 0.2
__device__ __constant__ float c_R2SOFT  = 0.25f;

// ---------------- rigid transform (3x4 row-major: r|t) ----------------
struct RT { float m[12]; };

__device__ inline RT rt_identity() {
    RT v;
    v.m[0]=1.f; v.m[1]=0.f; v.m[2]=0.f;  v.m[3]=0.f;
    v.m[4]=0.f; v.m[5]=1.f; v.m[6]=0.f;  v.m[7]=0.f;
    v.m[8]=0.f; v.m[9]=0.f; v.m[10]=1.f; v.m[11]=0.f;
    return v;
}

// C = A o B  (left-to-right chain product: cum = cum @ ht)
__device__ inline RT rt_compose(const RT& a, const RT& b) {
    RT c;
#pragma unroll
    for (int i = 0; i < 3; ++i) {
        float a0 = a.m[i*4+0], a1 = a.m[i*4+1], a2 = a.m[i*4+2];
        c.m[i*4+0] = fmaf(a0, b.m[0], fmaf(a1, b.m[4],  a2*b.m[8]));
        c.m[i*4+1] = fmaf(a0, b.m[1], fmaf(a1, b.m[5],  a2*b.m[9]));
        c.m[i*4+2] = fmaf(a0, b.m[2], fmaf(a1, b.m[6],  a2*b.m[10]));
        c.m[i*4+3] = fmaf(a0, b.m[3], fmaf(a1, b.m[7],  fmaf(a2, b.m[11], a.m[i*4+3])));
    }
    return c;
}

// lane-wise pull of an RT from (lane - off) within the wave
__device__ inline RT rt_shfl_up(const RT& a, int off) {
    RT r;
#pragma unroll
    for (int i = 0; i < 12; ++i) r.m[i] = __shfl_up(a.m[i], off, 64);
    return r;
}

// Accurate trig kept on purpose: the 4096-long compose chain amplifies per-HT
// error; absmax margin vs threshold is only ~2.2x.
__device__ inline RT local_ht(const float* __restrict__ dof) {
    float phi = dof[0], th = dof[1];
    float d = fmaf(0.25f, tanhf(dof[2]), 1.5f);
    float sp, cp, st, ct;
    sincosf(phi, &sp, &cp);
    sincosf(th,  &st, &ct);
    RT h;
    h.m[0] = cp*ct; h.m[1] = -sp; h.m[2]  = cp*st; h.m[3]  = d*cp*ct;
    h.m[4] = sp*ct; h.m[5] =  cp; h.m[6]  = sp*st; h.m[7]  = d*sp*ct;
    h.m[8] = -st;   h.m[9] = 0.f; h.m[10] = ct;    h.m[11] = -d*st;
    return h;
}

// ---------------- kernel 1a: per-segment inclusive scan (R3-verified) ----------
__global__ __launch_bounds__(SEG) void fk_scan(const float* __restrict__ dofs,
                                               float* __restrict__ Tx,
                                               float* __restrict__ Ty,
                                               float* __restrict__ Tz,
                                               float4* __restrict__ S0,
                                               float4* __restrict__ S1,
                                               float4* __restrict__ S2) {
    const int pose = blockIdx.x >> 6;        // NSEG = 64
    const int seg  = blockIdx.x & (NSEG - 1);
    const int lane = threadIdx.x;
    const int g    = pose * A_ATOMS + seg * SEG + lane;

    RT v = local_ht(dofs + (size_t)g * 9);

    // inclusive wave scan, earlier lane on the LEFT
#pragma unroll
    for (int off = 1; off < 64; off <<= 1) {
        RT l = rt_shfl_up(v, off);
        if (lane >= off) v = rt_compose(l, v);
    }

    // segment-relative translation for this atom (all that apply needs)
    Tx[g] = v.m[3]; Ty[g] = v.m[7]; Tz[g] = v.m[11];

    // segment total (full RT)
    if (lane == 63) {
        int s = pose * NSEG + seg;
        S0[s] = make_float4(v.m[0], v.m[1], v.m[2],  v.m[3]);
        S1[s] = make_float4(v.m[4], v.m[5], v.m[6],  v.m[7]);
        S2[s] = make_float4(v.m[8], v.m[9], v.m[10], v.m[11]);
    }
}

// ---------------- kernel 1b: totals scan + apply + scatter (R3-verified) --------
// Writes PACKED float4 (x,y,z,0): lj stages each atom with one dwordx4.
__global__ __launch_bounds__(APPLY_T) void fk_apply(const int* __restrict__ kid,
                                                    const float* __restrict__ Tx,
                                                    const float* __restrict__ Ty,
                                                    const float* __restrict__ Tz,
                                                    const float4* __restrict__ S0,
                                                    const float4* __restrict__ S1,
                                                    const float4* __restrict__ S2,
                                                    float4* __restrict__ C4,
                                                    float* __restrict__ out) {
    __shared__ float4 e0[NSEG], e1[NSEG], e2[NSEG];

    const int pose = blockIdx.y;
    const int blk  = blockIdx.x;
    const int tid  = threadIdx.x;
    if (blk == 0 && tid == 0) out[pose] = 0.f;

    if (tid < 64) {      // exactly wave 0: all 64 lanes active for shuffles
        int s = pose * NSEG + tid;
        float4 a0 = S0[s], a1 = S1[s], a2 = S2[s];
        RT v;
        v.m[0]=a0.x; v.m[1]=a0.y; v.m[2]=a0.z;  v.m[3]=a0.w;
        v.m[4]=a1.x; v.m[5]=a1.y; v.m[6]=a1.z;  v.m[7]=a1.w;
        v.m[8]=a2.x; v.m[9]=a2.y; v.m[10]=a2.z; v.m[11]=a2.w;
#pragma unroll
        for (int off = 1; off < 64; off <<= 1) {
            RT l = rt_shfl_up(v, off);
            if (tid >= off) v = rt_compose(l, v);
        }
        // exclusive prefix: shift right by one, identity at segment 0
        RT ex = rt_shfl_up(v, 1);
        if (tid == 0) ex = rt_identity();
        e0[tid] = make_float4(ex.m[0], ex.m[1], ex.m[2],  ex.m[3]);
        e1[tid] = make_float4(ex.m[4], ex.m[5], ex.m[6],  ex.m[7]);
        e2[tid] = make_float4(ex.m[8], ex.m[9], ex.m[10], ex.m[11]);
    }
    __syncthreads();

    const int a = blk * APPLY_T + tid;         // coalesced; a>>6 wave-uniform -> LDS broadcast
    const int g = pose * A_ATOMS + a;
    float rx = Tx[g], ry = Ty[g], rz = Tz[g];
    float4 x0 = e0[a >> 6], x1 = e1[a >> 6], x2 = e2[a >> 6];
    float tx = fmaf(x0.x, rx, fmaf(x0.y, ry, fmaf(x0.z, rz, x0.w)));
    float ty = fmaf(x1.x, rx, fmaf(x1.y, ry, fmaf(x1.z, rz, x1.w)));
    float tz = fmaf(x2.x, rx, fmaf(x2.y, ry, fmaf(x2.z, rz, x2.w)));
    C4[kid[g]] = make_float4(tx, ty, tz, 0.f);
}

// ---------------- kernel 2: LJ, one INDEPENDENT wave per 64x64 seg-pair ---------
// R6 diagnosis: every prior lj variant convoys 4-8 waves on a per-tile
// __syncthreads() + staging-load latency (VALUBusy 17%, 83% stall at near-full
// residency). This version removes inter-wave coupling: lane = one i-atom in
// registers; the wave's 64 j-atoms live in a private LDS slice read at
// wave-uniform addresses (broadcast, conflict-free). ONE barrier after staging
// (codegen fence) + one for the block reduce — none in the hot loop.
// 8320 waves (~8/SIMD) hide all remaining latency. Diagonal seg-pairs mask
// with lane < q (exact i<j). Block = 8 waves, pose-uniform (2080 % 8 == 0).
__global__ __launch_bounds__(LJW_T, 4) void lj_kernel(const float4* __restrict__ C4,
                                                      float* __restrict__ out) {
    __shared__ float4 jb[WPB][SEG];          // 8 KB: per-wave j-slice
    __shared__ float  wsum[WPB];

    const int tid  = threadIdx.x;
    const int lane = tid & 63;
    const int wid  = tid >> 6;

    // wave-uniform seg-pair id -> scalar regs (SALU row-walk)
    const int spi  = __builtin_amdgcn_readfirstlane(blockIdx.x * WPB + wid);
    const int pose = spi / SEGP_PER_POSE;
    int r  = spi - pose * SEGP_PER_POSE;
    int si = 0;
    while (r >= NSEG - si) { r -= NSEG - si; ++si; }
    const int sj = si + r;

    const float4* Cp = C4 + pose * A_ATOMS;
    float4 ci = Cp[si * SEG + lane];         // i-atom: registers
    jb[wid][lane] = Cp[sj * SEG + lane];     // j-atoms: wave-private LDS slice
    __syncthreads();                          // single staging fence

    const float SIG2 = c_SIGMA2, SOFT = c_R2SOFT;
    const float xi = ci.x, yi = ci.y, zi = ci.z;
    float acc = 0.f;

    if (si != sj) {
        const v2f soft2 = (v2f){SOFT, SOFT};
        v2f acc2 = (v2f){0.f, 0.f};
#pragma unroll
        for (int q = 0; q < SEG; q += 4) {
            float4 a = jb[wid][q + 0];       // uniform addr -> LDS broadcast
            float4 b = jb[wid][q + 1];
            float4 c = jb[wid][q + 2];
            float4 d = jb[wid][q + 3];
            {
                v2f xj = (v2f){a.x, b.x}, yj = (v2f){a.y, b.y}, zj = (v2f){a.z, b.z};
                v2f dx = xi - xj, dy = yi - yj, dz = zi - zj;
                v2f r2 = __builtin_elementwise_fma(dx, dx,
                         __builtin_elementwise_fma(dy, dy,
                         __builtin_elementwise_fma(dz, dz, soft2)));
                v2f rc = (v2f){__builtin_amdgcn_rcpf(r2.x), __builtin_amdgcn_rcpf(r2.y)};
                v2f tt = SIG2 * rc;
                v2f i6 = tt * tt * tt;
                acc2 += __builtin_elementwise_fma(i6, i6, -i6);   // inv12 - inv6
            }
            {
                v2f xj = (v2f){c.x, d.x}, yj = (v2f){c.y, d.y}, zj = (v2f){c.z, d.z};
                v2f dx = xi - xj, dy = yi - yj, dz = zi - zj;
                v2f r2 = __builtin_elementwise_fma(dx, dx,
                         __builtin_elementwise_fma(dy, dy,
                         __builtin_elementwise_fma(dz, dz, soft2)));
                v2f rc = (v2f){__builtin_amdgcn_rcpf(r2.x), __builtin_amdgcn_rcpf(r2.y)};
                v2f tt = SIG2 * rc;
                v2f i6 = tt * tt * tt;
                acc2 += __builtin_elementwise_fma(i6, i6, -i6);
            }
        }
        acc = acc2.x + acc2.y;
    } else {
        // diagonal seg-pair: i = si*64+lane, j = si*64+q -> keep lane < q
#pragma unroll 8
        for (int q = 0; q < SEG; ++q) {
            float4 a = jb[wid][q];
            float dx = xi - a.x, dy = yi - a.y, dz = zi - a.z;
            float r2 = fmaf(dx, dx, fmaf(dy, dy, fmaf(dz, dz, SOFT)));
            float tt = SIG2 * __builtin_amdgcn_rcpf(r2);
            float i6 = tt * tt * tt;
            float hh = fmaf(i6, i6, -i6);
            acc += (lane < q) ? hh : 0.f;
        }
    }
    acc *= c_4EPS;

    // wave reduce (intra-wave, no sync needed) then block reduce -> 1 atomic
#pragma unroll
    for (int off = 32; off > 0; off >>= 1) acc += __shfl_down(acc, off, 64);
    if (lane == 0) wsum[wid] = acc;
    __syncthreads();
    if (tid == 0) {
        float s = 0.f;
#pragma unroll
        for (int w = 0; w < WPB; ++w) s += wsum[w];
        atomicAdd(out + pose, s);
    }
}

// ---------------- launch ----------------
extern "C" void kernel_launch(void* const* d_in, const int* in_sizes, int n_in,
                              void* d_out, int out_size, void* d_ws, size_t ws_size,
                              hipStream_t stream) {
    (void)in_sizes; (void)n_in; (void)out_size; (void)ws_size;
    const float* dofs = (const float*)d_in[0];
    const int*   kid  = (const int*)d_in[2];
    float*       out  = (float*)d_out;

    // workspace layout (16B-aligned):
    //   C4:          N_TOT float4 (packed coords, kid-scattered)  256 KB
    //   Tx,Ty,Tz:    3 * N_TOT floats (segment-relative transl.)  192 KB
    //   S0,S1,S2:    3 * P*NSEG float4 (segment totals)            12 KB
    float4* C4 = (float4*)d_ws;
    float*  Tx = (float*)(C4 + N_TOT);
    float*  Ty = Tx + N_TOT;
    float*  Tz = Ty + N_TOT;
    float4* S0 = (float4*)(Tz + N_TOT);
    float4* S1 = S0 + P_POSES * NSEG;
    float4* S2 = S1 + P_POSES * NSEG;

    fk_scan<<<P_POSES * NSEG, SEG, 0, stream>>>(dofs, Tx, Ty, Tz, S0, S1, S2);
    dim3 agrid(APPLY_B, P_POSES);
    fk_apply<<<agrid, APPLY_T, 0, stream>>>(kid, Tx, Ty, Tz, S0, S1, S2, C4, out);
    lj_kernel<<<LJ_BLOCKS, LJW_T, 0, stream>>>(C4, out);
}

// Round 8
// 77.900 us; speedup vs baseline: 1.0239x; 1.0218x over previous
//
#include <hip/hip_runtime.h>
#include <math.h>

// Problem constants (setup_inputs is fixed: P=4, A=4096)
#define A_ATOMS 4096
#define P_POSES 4
#define N_TOT   (A_ATOMS * P_POSES)

// forward-kinematics segmented scan geometry (R3-verified structure)
#define SEG     64                            // atoms per segment = 1 wave
#define NSEG    (A_ATOMS / SEG)               // 64 segments per pose
#define APPLY_T 256                           // fk_apply threads (1 atom/thread)
#define APPLY_B (A_ATOMS / APPLY_T)           // 16 blocks per pose

// LJ wave-independent geometry: one wave per 64x64 segment-pair (R7-verified)
#define SEGP_PER_POSE (NSEG * (NSEG + 1) / 2) // 2080 upper-tri seg-pairs per pose
#define SEGP_TOT      (SEGP_PER_POSE * P_POSES) // 8320
#define LJW_T   512                           // 8 waves per block
#define WPB     (LJW_T / 64)                  // 8 seg-pairs per block
#define LJ_BLOCKS (SEGP_TOT / WPB)            // 1040
#define BLK_PER_POSE (SEGP_PER_POSE / WPB)    // 260 (pose-uniform blocks)

typedef float v2f __attribute__((ext_vector_type(2)));

__device__ __constant__ float c_SIGMA2  = 1.9f * 1.9f;
__device__ __constant__ float c_4EPS    = 0.8f;   // 4 * 0.2
__device__ __constant__ float c_R2SOFT  = 0.25f;

// ---------------- rigid transform (3x4 row-major: r|t) ----------------
struct RT { float m[12]; };

__device__ inline RT rt_identity() {
    RT v;
    v.m[0]=1.f; v.m[1]=0.f; v.m[2]=0.f;  v.m[3]=0.f;
    v.m[4]=0.f; v.m[5]=1.f; v.m[6]=0.f;  v.m[7]=0.f;
    v.m[8]=0.f; v.m[9]=0.f; v.m[10]=1.f; v.m[11]=0.f;
    return v;
}

// C = A o B  (left-to-right chain product: cum = cum @ ht)
__device__ inline RT rt_compose(const RT& a, const RT& b) {
    RT c;
#pragma unroll
    for (int i = 0; i < 3; ++i) {
        float a0 = a.m[i*4+0], a1 = a.m[i*4+1], a2 = a.m[i*4+2];
        c.m[i*4+0] = fmaf(a0, b.m[0], fmaf(a1, b.m[4],  a2*b.m[8]));
        c.m[i*4+1] = fmaf(a0, b.m[1], fmaf(a1, b.m[5],  a2*b.m[9]));
        c.m[i*4+2] = fmaf(a0, b.m[2], fmaf(a1, b.m[6],  a2*b.m[10]));
        c.m[i*4+3] = fmaf(a0, b.m[3], fmaf(a1, b.m[7],  fmaf(a2, b.m[11], a.m[i*4+3])));
    }
    return c;
}

// lane-wise pull of an RT from (lane - off) within the wave
__device__ inline RT rt_shfl_up(const RT& a, int off) {
    RT r;
#pragma unroll
    for (int i = 0; i < 12; ++i) r.m[i] = __shfl_up(a.m[i], off, 64);
    return r;
}

// Accurate trig kept on purpose: the 4096-long compose chain amplifies per-HT
// error; absmax margin vs threshold is only ~2.2x.
__device__ inline RT local_ht(const float* __restrict__ dof) {
    float phi = dof[0], th = dof[1];
    float d = fmaf(0.25f, tanhf(dof[2]), 1.5f);
    float sp, cp, st, ct;
    sincosf(phi, &sp, &cp);
    sincosf(th,  &st, &ct);
    RT h;
    h.m[0] = cp*ct; h.m[1] = -sp; h.m[2]  = cp*st; h.m[3]  = d*cp*ct;
    h.m[4] = sp*ct; h.m[5] =  cp; h.m[6]  = sp*st; h.m[7]  = d*sp*ct;
    h.m[8] = -st;   h.m[9] = 0.f; h.m[10] = ct;    h.m[11] = -d*st;
    return h;
}

// ---------------- kernel 1a: per-segment inclusive scan (R3-verified) ----------
__global__ __launch_bounds__(SEG) void fk_scan(const float* __restrict__ dofs,
                                               float* __restrict__ Tx,
                                               float* __restrict__ Ty,
                                               float* __restrict__ Tz,
                                               float4* __restrict__ S0,
                                               float4* __restrict__ S1,
                                               float4* __restrict__ S2) {
    const int pose = blockIdx.x >> 6;        // NSEG = 64
    const int seg  = blockIdx.x & (NSEG - 1);
    const int lane = threadIdx.x;
    const int g    = pose * A_ATOMS + seg * SEG + lane;

    RT v = local_ht(dofs + (size_t)g * 9);

    // inclusive wave scan, earlier lane on the LEFT
#pragma unroll
    for (int off = 1; off < 64; off <<= 1) {
        RT l = rt_shfl_up(v, off);
        if (lane >= off) v = rt_compose(l, v);
    }

    // segment-relative translation for this atom (all that apply needs)
    Tx[g] = v.m[3]; Ty[g] = v.m[7]; Tz[g] = v.m[11];

    // segment total (full RT)
    if (lane == 63) {
        int s = pose * NSEG + seg;
        S0[s] = make_float4(v.m[0], v.m[1], v.m[2],  v.m[3]);
        S1[s] = make_float4(v.m[4], v.m[5], v.m[6],  v.m[7]);
        S2[s] = make_float4(v.m[8], v.m[9], v.m[10], v.m[11]);
    }
}

// ---------------- kernel 1b: totals scan + apply + scatter (R3-verified) --------
// Writes PACKED float4 (x,y,z,0): lj stages each atom with one dwordx4.
// (out-zeroing removed: the final reduce kernel STORES out, no accumulation.)
__global__ __launch_bounds__(APPLY_T) void fk_apply(const int* __restrict__ kid,
                                                    const float* __restrict__ Tx,
                                                    const float* __restrict__ Ty,
                                                    const float* __restrict__ Tz,
                                                    const float4* __restrict__ S0,
                                                    const float4* __restrict__ S1,
                                                    const float4* __restrict__ S2,
                                                    float4* __restrict__ C4) {
    __shared__ float4 e0[NSEG], e1[NSEG], e2[NSEG];

    const int pose = blockIdx.y;
    const int blk  = blockIdx.x;
    const int tid  = threadIdx.x;

    if (tid < 64) {      // exactly wave 0: all 64 lanes active for shuffles
        int s = pose * NSEG + tid;
        float4 a0 = S0[s], a1 = S1[s], a2 = S2[s];
        RT v;
        v.m[0]=a0.x; v.m[1]=a0.y; v.m[2]=a0.z;  v.m[3]=a0.w;
        v.m[4]=a1.x; v.m[5]=a1.y; v.m[6]=a1.z;  v.m[7]=a1.w;
        v.m[8]=a2.x; v.m[9]=a2.y; v.m[10]=a2.z; v.m[11]=a2.w;
#pragma unroll
        for (int off = 1; off < 64; off <<= 1) {
            RT l = rt_shfl_up(v, off);
            if (tid >= off) v = rt_compose(l, v);
        }
        // exclusive prefix: shift right by one, identity at segment 0
        RT ex = rt_shfl_up(v, 1);
        if (tid == 0) ex = rt_identity();
        e0[tid] = make_float4(ex.m[0], ex.m[1], ex.m[2],  ex.m[3]);
        e1[tid] = make_float4(ex.m[4], ex.m[5], ex.m[6],  ex.m[7]);
        e2[tid] = make_float4(ex.m[8], ex.m[9], ex.m[10], ex.m[11]);
    }
    __syncthreads();

    const int a = blk * APPLY_T + tid;         // coalesced; a>>6 wave-uniform -> LDS broadcast
    const int g = pose * A_ATOMS + a;
    float rx = Tx[g], ry = Ty[g], rz = Tz[g];
    float4 x0 = e0[a >> 6], x1 = e1[a >> 6], x2 = e2[a >> 6];
    float tx = fmaf(x0.x, rx, fmaf(x0.y, ry, fmaf(x0.z, rz, x0.w)));
    float ty = fmaf(x1.x, rx, fmaf(x1.y, ry, fmaf(x1.z, rz, x1.w)));
    float tz = fmaf(x2.x, rx, fmaf(x2.y, ry, fmaf(x2.z, rz, x2.w)));
    C4[kid[g]] = make_float4(tx, ty, tz, 0.f);
}

// ---------------- kernel 2: LJ, one INDEPENDENT wave per 64x64 seg-pair ---------
// R7-verified compute. SINGLE CHANGE this round: the device-scope atomicAdd
// (260 same-address RMWs per pose converging from all 8 XCDs — the prime
// suspect for the invariant ~25 us residual across three lj geometries) is
// replaced by one contention-free store per block into partial[blockIdx.x];
// a tiny 4th kernel reduces the 260 partials per pose.
__global__ __launch_bounds__(LJW_T, 4) void lj_kernel(const float4* __restrict__ C4,
                                                      float* __restrict__ partial) {
    __shared__ float4 jb[WPB][SEG];          // 8 KB: per-wave j-slice
    __shared__ float  wsum[WPB];

    const int tid  = threadIdx.x;
    const int lane = tid & 63;
    const int wid  = tid >> 6;

    // wave-uniform seg-pair id -> scalar regs (SALU row-walk)
    const int spi  = __builtin_amdgcn_readfirstlane(blockIdx.x * WPB + wid);
    const int pose = spi / SEGP_PER_POSE;
    int r  = spi - pose * SEGP_PER_POSE;
    int si = 0;
    while (r >= NSEG - si) { r -= NSEG - si; ++si; }
    const int sj = si + r;

    const float4* Cp = C4 + pose * A_ATOMS;
    float4 ci = Cp[si * SEG + lane];         // i-atom: registers
    jb[wid][lane] = Cp[sj * SEG + lane];     // j-atoms: wave-private LDS slice
    __syncthreads();                          // single staging fence

    const float SIG2 = c_SIGMA2, SOFT = c_R2SOFT;
    const float xi = ci.x, yi = ci.y, zi = ci.z;
    float acc = 0.f;

    if (si != sj) {
        const v2f soft2 = (v2f){SOFT, SOFT};
        v2f acc2 = (v2f){0.f, 0.f};
#pragma unroll
        for (int q = 0; q < SEG; q += 4) {
            float4 a = jb[wid][q + 0];       // uniform addr -> LDS broadcast
            float4 b = jb[wid][q + 1];
            float4 c = jb[wid][q + 2];
            float4 d = jb[wid][q + 3];
            {
                v2f xj = (v2f){a.x, b.x}, yj = (v2f){a.y, b.y}, zj = (v2f){a.z, b.z};
                v2f dx = xi - xj, dy = yi - yj, dz = zi - zj;
                v2f r2 = __builtin_elementwise_fma(dx, dx,
                         __builtin_elementwise_fma(dy, dy,
                         __builtin_elementwise_fma(dz, dz, soft2)));
                v2f rc = (v2f){__builtin_amdgcn_rcpf(r2.x), __builtin_amdgcn_rcpf(r2.y)};
                v2f tt = SIG2 * rc;
                v2f i6 = tt * tt * tt;
                acc2 += __builtin_elementwise_fma(i6, i6, -i6);   // inv12 - inv6
            }
            {
                v2f xj = (v2f){c.x, d.x}, yj = (v2f){c.y, d.y}, zj = (v2f){c.z, d.z};
                v2f dx = xi - xj, dy = yi - yj, dz = zi - zj;
                v2f r2 = __builtin_elementwise_fma(dx, dx,
                         __builtin_elementwise_fma(dy, dy,
                         __builtin_elementwise_fma(dz, dz, soft2)));
                v2f rc = (v2f){__builtin_amdgcn_rcpf(r2.x), __builtin_amdgcn_rcpf(r2.y)};
                v2f tt = SIG2 * rc;
                v2f i6 = tt * tt * tt;
                acc2 += __builtin_elementwise_fma(i6, i6, -i6);
            }
        }
        acc = acc2.x + acc2.y;
    } else {
        // diagonal seg-pair: i = si*64+lane, j = si*64+q -> keep lane < q
#pragma unroll 8
        for (int q = 0; q < SEG; ++q) {
            float4 a = jb[wid][q];
            float dx = xi - a.x, dy = yi - a.y, dz = zi - a.z;
            float r2 = fmaf(dx, dx, fmaf(dy, dy, fmaf(dz, dz, SOFT)));
            float tt = SIG2 * __builtin_amdgcn_rcpf(r2);
            float i6 = tt * tt * tt;
            float hh = fmaf(i6, i6, -i6);
            acc += (lane < q) ? hh : 0.f;
        }
    }
    acc *= c_4EPS;

    // wave reduce (intra-wave, no sync needed) then block reduce -> ONE STORE
#pragma unroll
    for (int off = 32; off > 0; off >>= 1) acc += __shfl_down(acc, off, 64);
    if (lane == 0) wsum[wid] = acc;
    __syncthreads();
    if (tid == 0) {
        float s = 0.f;
#pragma unroll
        for (int w = 0; w < WPB; ++w) s += wsum[w];
        partial[blockIdx.x] = s;             // contention-free
    }
}

// ---------------- kernel 3: per-pose partial reduce (4 blocks x 256) ------------
// Block p sums partial[p*260 .. p*260+259] and STORES out[p] (no atomics,
// no prior zeroing needed anywhere).
__global__ __launch_bounds__(256) void lj_reduce(const float* __restrict__ partial,
                                                 float* __restrict__ out) {
    __shared__ float wsum[4];
    const int pose = blockIdx.x;
    const int tid  = threadIdx.x;

    float acc = 0.f;
    for (int i = tid; i < BLK_PER_POSE; i += 256) acc += partial[pose * BLK_PER_POSE + i];

#pragma unroll
    for (int off = 32; off > 0; off >>= 1) acc += __shfl_down(acc, off, 64);
    int lane = tid & 63, wid = tid >> 6;
    if (lane == 0) wsum[wid] = acc;
    __syncthreads();
    if (tid == 0) out[pose] = wsum[0] + wsum[1] + wsum[2] + wsum[3];
}

// ---------------- launch ----------------
extern "C" void kernel_launch(void* const* d_in, const int* in_sizes, int n_in,
                              void* d_out, int out_size, void* d_ws, size_t ws_size,
                              hipStream_t stream) {
    (void)in_sizes; (void)n_in; (void)out_size; (void)ws_size;
    const float* dofs = (const float*)d_in[0];
    const int*   kid  = (const int*)d_in[2];
    float*       out  = (float*)d_out;

    // workspace layout (16B-aligned):
    //   C4:          N_TOT float4 (packed coords, kid-scattered)  256 KB
    //   Tx,Ty,Tz:    3 * N_TOT floats (segment-relative transl.)  192 KB
    //   S0,S1,S2:    3 * P*NSEG float4 (segment totals)            12 KB
    //   partial:     LJ_BLOCKS floats (block sums)                  4 KB
    float4* C4 = (float4*)d_ws;
    float*  Tx = (float*)(C4 + N_TOT);
    float*  Ty = Tx + N_TOT;
    float*  Tz = Ty + N_TOT;
    float4* S0 = (float4*)(Tz + N_TOT);
    float4* S1 = S0 + P_POSES * NSEG;
    float4* S2 = S1 + P_POSES * NSEG;
    float*  partial = (float*)(S2 + P_POSES * NSEG);

    fk_scan<<<P_POSES * NSEG, SEG, 0, stream>>>(dofs, Tx, Ty, Tz, S0, S1, S2);
    dim3 agrid(APPLY_B, P_POSES);
    fk_apply<<<agrid, APPLY_T, 0, stream>>>(kid, Tx, Ty, Tz, S0, S1, S2, C4);
    lj_kernel<<<LJ_BLOCKS, LJW_T, 0, stream>>>(C4, partial);
    lj_reduce<<<P_POSES, 256, 0, stream>>>(partial, out);
}